// Round 2
// baseline (404.971 us; speedup 1.0000x reference)
//
#include <hip/hip_runtime.h>

// Problem constants
#define T_LEN 4096
#define DMODEL 512
#define DIM 512
#define NBATCH 8
#define MROWS (NBATCH * T_LEN)   // 32768
#define NCHUNK 64
#define LCHUNK 64                 // T_LEN / NCHUNK

typedef __attribute__((ext_vector_type(8))) short short8;
typedef __attribute__((ext_vector_type(4))) float float4v;

__device__ __forceinline__ ushort f2b(float f) {
    union { float fl; unsigned u; } v; v.fl = f;
    unsigned u = v.u;
    return (ushort)((u + 0x7FFFu + ((u >> 16) & 1u)) >> 16);
}

// ---------------- prep kernels ----------------

// x fp32 -> bf16 (4 elems/thread)
__global__ __launch_bounds__(256) void k_prep_x(const float* __restrict__ x,
                                                ushort* __restrict__ xb) {
    int i = (blockIdx.x * 256 + threadIdx.x) * 4;
    float4 v = *(const float4*)(x + i);
    ushort4 o;
    o.x = f2b(v.x); o.y = f2b(v.y); o.z = f2b(v.z); o.w = f2b(v.w);
    *(ushort4*)(xb + i) = o;
}

// BcatT[n][d] (1024 x 512, bf16): n<512 -> B_re[d][n]*exp(g[n]); else B_im[d][n-512]*exp(g[n-512])
__global__ __launch_bounds__(256) void k_prep_B(const float* __restrict__ Bre,
                                                const float* __restrict__ Bim,
                                                const float* __restrict__ gamma_log,
                                                ushort* __restrict__ BT) {
    int idx = blockIdx.x * 256 + threadIdx.x;   // 0 .. 1024*512-1
    int n = idx >> 9;        // 0..1023
    int d = idx & 511;
    float v;
    if (n < 512) v = Bre[d * 512 + n] * __expf(gamma_log[n]);
    else { int nn = n - 512; v = Bim[d * 512 + nn] * __expf(gamma_log[nn]); }
    BT[idx] = f2b(v);
}

// CcatT[d][k] (512 x 1024, bf16): k<512 -> C_re[k][d]; else -C_im[k-512][d]
__global__ __launch_bounds__(256) void k_prep_C(const float* __restrict__ Cre,
                                                const float* __restrict__ Cim,
                                                ushort* __restrict__ CT) {
    int idx = blockIdx.x * 256 + threadIdx.x;   // 0 .. 512*1024-1
    int d = idx >> 10;       // 0..511
    int k = idx & 1023;
    float v = (k < 512) ? Cre[k * 512 + d] : -Cim[(k - 512) * 512 + d];
    CT[idx] = f2b(v);
}

// ---------------- bf16 MFMA GEMM, A (MxK row-major) * Bt^T (Bt is NxK row-major) ----------------
// BM=BN=128, BK=32, 256 threads = 4 waves in 2x2, each wave 64x64 via 4x4 MFMA 16x16x32.
__global__ __launch_bounds__(256) void k_gemm(
    const ushort* __restrict__ A, const ushort* __restrict__ Bt, int K, int mode,
    float* __restrict__ oRe, float* __restrict__ oIm,
    float* __restrict__ y, const float* __restrict__ x, const float* __restrict__ Dp) {
    __shared__ ushort sA[128][32];
    __shared__ ushort sB[128][32];
    const int tid = threadIdx.x;
    const int m0 = blockIdx.y * 128;
    const int n0 = blockIdx.x * 128;
    const int wave = tid >> 6;
    const int lane = tid & 63;
    const int wm = (wave >> 1) * 64;
    const int wn = (wave & 1) * 64;
    const int lr = lane & 15;
    const int quad = lane >> 4;

    float4v acc[4][4];
#pragma unroll
    for (int i = 0; i < 4; i++)
#pragma unroll
        for (int j = 0; j < 4; j++) {
            float4v z = {0.f, 0.f, 0.f, 0.f};
            acc[i][j] = z;
        }

    for (int k0 = 0; k0 < K; k0 += 32) {
        __syncthreads();
#pragma unroll
        for (int s = 0; s < 2; s++) {
            int seg = tid + s * 256;        // 0..511
            int row = seg >> 2;
            int cs = (seg & 3) * 8;         // bf16 elem offset within 32-col row
            *(uint4*)&sA[row][cs] = *(const uint4*)(A + (size_t)(m0 + row) * K + k0 + cs);
            *(uint4*)&sB[row][cs] = *(const uint4*)(Bt + (size_t)(n0 + row) * K + k0 + cs);
        }
        __syncthreads();

        short8 af[4], bfr[4];
#pragma unroll
        for (int i = 0; i < 4; i++) af[i] = *(const short8*)&sA[wm + i * 16 + lr][quad * 8];
#pragma unroll
        for (int j = 0; j < 4; j++) bfr[j] = *(const short8*)&sB[wn + j * 16 + lr][quad * 8];
#pragma unroll
        for (int i = 0; i < 4; i++)
#pragma unroll
            for (int j = 0; j < 4; j++)
                acc[i][j] = __builtin_amdgcn_mfma_f32_16x16x32_bf16(af[i], bfr[j], acc[i][j], 0, 0, 0);
    }

    // epilogue: D[row][col], col = lane&15, row = quad*4 + r
#pragma unroll
    for (int i = 0; i < 4; i++) {
#pragma unroll
        for (int j = 0; j < 4; j++) {
            int gmb = m0 + wm + i * 16 + quad * 4;
            int gn = n0 + wn + j * 16 + lr;
#pragma unroll
            for (int r = 0; r < 4; r++) {
                float v = acc[i][j][r];
                int row = gmb + r;
                if (mode == 1) {
                    if (gn < 512) oRe[(size_t)row * 512 + gn] = v;
                    else oIm[(size_t)row * 512 + (gn - 512)] = v;
                } else {
                    size_t o = (size_t)row * 512 + gn;
                    y[o] = v + Dp[gn] * x[o];
                }
            }
        }
    }
}

// ---------------- scan kernels ----------------

__device__ __forceinline__ void lambda_of(const float* nu_log, const float* theta_log,
                                          int n, float& lre, float& lim) {
    float e = __expf(nu_log[n]);
    float th = __expf(theta_log[n]);
    float rad = __expf(-e);
    float s, c;
    __sincosf(th, &s, &c);
    lre = rad * c;
    lim = rad * s;
}

// phase 1: per (b, chunk, n) local scan from zero state -> chunk-final carry
__global__ __launch_bounds__(512) void k_scan1(const float* __restrict__ BuRe,
                                               const float* __restrict__ BuIm,
                                               const float* __restrict__ nu_log,
                                               const float* __restrict__ theta_log,
                                               float* __restrict__ cRe, float* __restrict__ cIm) {
    int n = threadIdx.x;
    int b = blockIdx.x >> 6;
    int c = blockIdx.x & 63;
    float lre, lim;
    lambda_of(nu_log, theta_log, n, lre, lim);
    float hr = 0.f, hi = 0.f;
    size_t base = ((size_t)b * T_LEN + (size_t)c * LCHUNK) * 512 + n;
    for (int j = 0; j < LCHUNK; j++) {
        float br = BuRe[base + (size_t)j * 512];
        float bi = BuIm[base + (size_t)j * 512];
        float nr = lre * hr - lim * hi + br;
        float ni = lre * hi + lim * hr + bi;
        hr = nr; hi = ni;
    }
    size_t co = ((size_t)b * NCHUNK + c) * 512 + n;
    cRe[co] = hr;
    cIm[co] = hi;
}

// phase 2: combine carries sequentially across chunks; emit per-chunk entering state and new_h
// newh_mode: 0 = interleaved (re,im) pairs; 1 = planar [all re][all im]; 2 = real only
__global__ __launch_bounds__(256) void k_scan2(const float* __restrict__ cRe,
                                               const float* __restrict__ cIm,
                                               const float* __restrict__ h0,
                                               const float* __restrict__ nu_log,
                                               const float* __restrict__ theta_log,
                                               float* __restrict__ pRe, float* __restrict__ pIm,
                                               float* __restrict__ newH, int newh_mode) {
    int idx = blockIdx.x * 256 + threadIdx.x;   // 0..4095
    int b = idx >> 9;
    int n = idx & 511;
    float lre, lim;
    lambda_of(nu_log, theta_log, n, lre, lim);
    // lambda^LCHUNK via 6 squarings (LCHUNK = 64)
    float Lr = lre, Li = lim;
#pragma unroll
    for (int s = 0; s < 6; s++) {
        float nr = Lr * Lr - Li * Li;
        float ni = 2.f * Lr * Li;
        Lr = nr; Li = ni;
    }
    float cr = h0[b * 512 + n];
    float ci = 0.f;
    for (int c = 0; c < NCHUNK; c++) {
        size_t o = ((size_t)b * NCHUNK + c) * 512 + n;
        pRe[o] = cr;
        pIm[o] = ci;
        float ar = cRe[o], ai = cIm[o];
        float nr = Lr * cr - Li * ci + ar;
        float ni = Lr * ci + Li * cr + ai;
        cr = nr; ci = ni;
    }
    // new_h, shape (8,1,512) complex
    size_t ci_idx = (size_t)b * 512 + n;
    if (newh_mode == 1) {
        newH[ci_idx] = cr;
        newH[(size_t)NBATCH * 512 + ci_idx] = ci;
    } else if (newh_mode == 2) {
        newH[ci_idx] = cr;
    } else {
        newH[ci_idx * 2] = cr;
        newH[ci_idx * 2 + 1] = ci;
    }
}

// phase 3: recompute local scan, add lambda^{j+1} * entering-state, write H as bf16 concat [re | im]
__global__ __launch_bounds__(512) void k_scan3(const float* __restrict__ BuRe,
                                               const float* __restrict__ BuIm,
                                               const float* __restrict__ pRe,
                                               const float* __restrict__ pIm,
                                               const float* __restrict__ nu_log,
                                               const float* __restrict__ theta_log,
                                               ushort* __restrict__ Hbf) {
    int n = threadIdx.x;
    int b = blockIdx.x >> 6;
    int c = blockIdx.x & 63;
    float lre, lim;
    lambda_of(nu_log, theta_log, n, lre, lim);
    size_t co = ((size_t)b * NCHUNK + c) * 512 + n;
    float fr = pRe[co], fi = pIm[co];
    float pr = lre, pi = lim;   // lambda^{j+1}
    float hr = 0.f, hi = 0.f;
    size_t base = ((size_t)b * T_LEN + (size_t)c * LCHUNK) * 512 + n;
    for (int j = 0; j < LCHUNK; j++) {
        float br = BuRe[base + (size_t)j * 512];
        float bi = BuIm[base + (size_t)j * 512];
        float nr = lre * hr - lim * hi + br;
        float ni = lre * hi + lim * hr + bi;
        hr = nr; hi = ni;
        float vr = hr + pr * fr - pi * fi;
        float vi = hi + pr * fi + pi * fr;
        size_t hrow = (base + (size_t)j * 512 - n) * 2;   // row*1024
        Hbf[hrow + n] = f2b(vr);
        Hbf[hrow + 512 + n] = f2b(vi);
        float npr = pr * lre - pi * lim;
        float npi = pr * lim + pi * lre;
        pr = npr; pi = npi;
    }
}

// ---------------- launch ----------------

extern "C" void kernel_launch(void* const* d_in, const int* in_sizes, int n_in,
                              void* d_out, int out_size, void* d_ws, size_t ws_size,
                              hipStream_t stream) {
    const float* x         = (const float*)d_in[0];
    const float* h0        = (const float*)d_in[1];
    const float* nu_log    = (const float*)d_in[2];
    const float* theta_log = (const float*)d_in[3];
    const float* B_re      = (const float*)d_in[4];
    const float* B_im      = (const float*)d_in[5];
    const float* C_re      = (const float*)d_in[6];
    const float* C_im      = (const float*)d_in[7];
    const float* D_param   = (const float*)d_in[8];
    const float* gamma_log = (const float*)d_in[9];

    char* ws = (char*)d_ws;
    size_t off = 0;
    ushort* Xb  = (ushort*)(ws + off); off += (size_t)MROWS * 512 * 2;        // 32 MB
    ushort* BT  = (ushort*)(ws + off); off += (size_t)1024 * 512 * 2;         // 1 MB
    ushort* CT  = (ushort*)(ws + off); off += (size_t)512 * 1024 * 2;         // 1 MB
    float*  BuRe = (float*)(ws + off); off += (size_t)MROWS * 512 * 4;        // 64 MB
    float*  BuIm = (float*)(ws + off); off += (size_t)MROWS * 512 * 4;        // 64 MB
    ushort* Hbf = (ushort*)(ws + off); off += (size_t)MROWS * 1024 * 2;       // 64 MB
    float*  cRe = (float*)(ws + off); off += (size_t)NBATCH * NCHUNK * 512 * 4;
    float*  cIm = (float*)(ws + off); off += (size_t)NBATCH * NCHUNK * 512 * 4;
    float*  pRe = (float*)(ws + off); off += (size_t)NBATCH * NCHUNK * 512 * 4;
    float*  pIm = (float*)(ws + off); off += (size_t)NBATCH * NCHUNK * 512 * 4;

    float* y_out = (float*)d_out;
    float* newH  = (float*)d_out + (size_t)MROWS * 512;

    // Discriminate the harness's complex64 flattening by out_size.
    // tail 8192 floats -> planar [re|im] (interleaved measured wrong in R1);
    // tail 4096 floats -> real-part-only; otherwise fall back to interleaved.
    const int tail = out_size - MROWS * 512;
    int newh_mode = 0;
    if (tail == NBATCH * 512 * 2) newh_mode = 1;
    else if (tail == NBATCH * 512) newh_mode = 2;

    // prep
    k_prep_x<<<dim3(MROWS * 512 / 4 / 256), dim3(256), 0, stream>>>(x, Xb);
    k_prep_B<<<dim3(1024 * 512 / 256), dim3(256), 0, stream>>>(B_re, B_im, gamma_log, BT);
    k_prep_C<<<dim3(512 * 1024 / 256), dim3(256), 0, stream>>>(C_re, C_im, CT);

    // GEMM1: Bu = Xb (32768x512) * BcatT^T (512x1024) -> Bu planes
    k_gemm<<<dim3(1024 / 128, MROWS / 128), dim3(256), 0, stream>>>(
        Xb, BT, 512, 1, BuRe, BuIm, nullptr, nullptr, nullptr);

    // scan
    k_scan1<<<dim3(NBATCH * NCHUNK), dim3(512), 0, stream>>>(BuRe, BuIm, nu_log, theta_log, cRe, cIm);
    k_scan2<<<dim3(NBATCH * 512 / 256), dim3(256), 0, stream>>>(cRe, cIm, h0, nu_log, theta_log, pRe, pIm, newH, newh_mode);
    k_scan3<<<dim3(NBATCH * NCHUNK), dim3(512), 0, stream>>>(BuRe, BuIm, pRe, pIm, nu_log, theta_log, Hbf);

    // GEMM2: y = Hbf (32768x1024) * CcatT^T (1024x512) + D*x
    k_gemm<<<dim3(512 / 128, MROWS / 128), dim3(256), 0, stream>>>(
        Hbf, CT, 1024, 2, nullptr, nullptr, y_out, x, D_param);
}

// Round 3
// 315.885 us; speedup vs baseline: 1.2820x; 1.2820x over previous
//
#include <hip/hip_runtime.h>

// Problem constants
#define T_LEN 4096
#define DMODEL 512
#define DIM 512
#define NBATCH 8
#define MROWS (NBATCH * T_LEN)   // 32768
#define NCHUNK 128
#define LCHUNK 32                 // T_LEN / NCHUNK

typedef __attribute__((ext_vector_type(8))) short short8;
typedef __attribute__((ext_vector_type(4))) float float4v;

__device__ __forceinline__ ushort f2b(float f) {
    union { float fl; unsigned u; } v; v.fl = f;
    unsigned u = v.u;
    return (ushort)((u + 0x7FFFu + ((u >> 16) & 1u)) >> 16);
}
__device__ __forceinline__ float b2f(ushort u) {
    union { unsigned u; float f; } v; v.u = (unsigned)u << 16; return v.f;
}

// async global->LDS, 16B per lane; LDS dest = wave-uniform base + lane*16
__device__ __forceinline__ void glds16(const ushort* g, ushort* l) {
    __builtin_amdgcn_global_load_lds(
        (const __attribute__((address_space(1))) void*)g,
        (__attribute__((address_space(3))) void*)l, 16, 0, 0);
}

// ---------------- prep kernels ----------------

__global__ __launch_bounds__(256) void k_prep_x(const float* __restrict__ x,
                                                ushort* __restrict__ xb) {
    int i = (blockIdx.x * 256 + threadIdx.x) * 4;
    float4 v = *(const float4*)(x + i);
    ushort4 o;
    o.x = f2b(v.x); o.y = f2b(v.y); o.z = f2b(v.z); o.w = f2b(v.w);
    *(ushort4*)(xb + i) = o;
}

__global__ __launch_bounds__(256) void k_prep_B(const float* __restrict__ Bre,
                                                const float* __restrict__ Bim,
                                                const float* __restrict__ gamma_log,
                                                ushort* __restrict__ BT) {
    int idx = blockIdx.x * 256 + threadIdx.x;   // 0 .. 1024*512-1
    int n = idx >> 9;
    int d = idx & 511;
    float v;
    if (n < 512) v = Bre[d * 512 + n] * __expf(gamma_log[n]);
    else { int nn = n - 512; v = Bim[d * 512 + nn] * __expf(gamma_log[nn]); }
    BT[idx] = f2b(v);
}

__global__ __launch_bounds__(256) void k_prep_C(const float* __restrict__ Cre,
                                                const float* __restrict__ Cim,
                                                ushort* __restrict__ CT) {
    int idx = blockIdx.x * 256 + threadIdx.x;   // 0 .. 512*1024-1
    int d = idx >> 10;
    int k = idx & 1023;
    float v = (k < 512) ? Cre[k * 512 + d] : -Cim[(k - 512) * 512 + d];
    CT[idx] = f2b(v);
}

// ---------------- bf16 MFMA GEMM (m97 structure): A (MxK rm) * Bt^T (Bt NxK rm) ----------------
// BM=BN=128, BK=32, 256 thr = 4 waves 2x2, wave = 64x64 via 4x4 MFMA 16x16x32.
// Staging via global_load_lds width=16: lane-ordered LDS layout [row][32] unpadded.
template<int K, int MODE>
__global__ __launch_bounds__(256) void k_gemm(
    const ushort* __restrict__ A, const ushort* __restrict__ Bt,
    ushort* __restrict__ oRe, ushort* __restrict__ oIm,
    float* __restrict__ y, const float* __restrict__ x, const float* __restrict__ Dp) {
    __shared__ ushort sA[128 * 32];
    __shared__ ushort sB[128 * 32];
    const int tid = threadIdx.x;
    const int m0 = blockIdx.y * 128;
    const int n0 = blockIdx.x * 128;
    const int wave = tid >> 6;
    const int lane = tid & 63;
    const int wm = (wave >> 1) * 64;
    const int wn = (wave & 1) * 64;
    const int lr = lane & 15;
    const int quad = lane >> 4;

    // staging: wave w covers rows [w*32, w*32+32) of each tile in 2 calls of 16 rows
    const int srow = wave * 32 + (lane >> 2);
    const int scol = (lane & 3) * 8;
    const ushort* gA0 = A + (size_t)(m0 + srow) * K + scol;
    const ushort* gB0 = Bt + (size_t)(n0 + srow) * K + scol;
    ushort* lA0 = &sA[(wave * 32) * 32];
    ushort* lA1 = &sA[(wave * 32 + 16) * 32];
    ushort* lB0 = &sB[(wave * 32) * 32];
    ushort* lB1 = &sB[(wave * 32 + 16) * 32];

    float4v acc[4][4];
#pragma unroll
    for (int i = 0; i < 4; i++)
#pragma unroll
        for (int j = 0; j < 4; j++) {
            float4v z = {0.f, 0.f, 0.f, 0.f};
            acc[i][j] = z;
        }

    for (int k0 = 0; k0 < K; k0 += 32) {
        __syncthreads();
        glds16(gA0 + k0, lA0);
        glds16(gA0 + (size_t)16 * K + k0, lA1);
        glds16(gB0 + k0, lB0);
        glds16(gB0 + (size_t)16 * K + k0, lB1);
        __syncthreads();

        short8 af[4], bfr[4];
#pragma unroll
        for (int i = 0; i < 4; i++) af[i] = *(const short8*)&sA[(wm + i * 16 + lr) * 32 + quad * 8];
#pragma unroll
        for (int j = 0; j < 4; j++) bfr[j] = *(const short8*)&sB[(wn + j * 16 + lr) * 32 + quad * 8];
#pragma unroll
        for (int i = 0; i < 4; i++)
#pragma unroll
            for (int j = 0; j < 4; j++)
                acc[i][j] = __builtin_amdgcn_mfma_f32_16x16x32_bf16(af[i], bfr[j], acc[i][j], 0, 0, 0);
    }

    // epilogue: D[row][col], col = lane&15, row = quad*4 + r
#pragma unroll
    for (int i = 0; i < 4; i++) {
#pragma unroll
        for (int j = 0; j < 4; j++) {
            int gmb = m0 + wm + i * 16 + quad * 4;
            int gn = n0 + wn + j * 16 + lr;
#pragma unroll
            for (int r = 0; r < 4; r++) {
                float v = acc[i][j][r];
                int row = gmb + r;
                if (MODE == 1) {
                    if (gn < 512) oRe[(size_t)row * 512 + gn] = f2b(v);
                    else oIm[(size_t)row * 512 + (gn - 512)] = f2b(v);
                } else {
                    size_t o = (size_t)row * 512 + gn;
                    y[o] = v + Dp[gn] * x[o];
                }
            }
        }
    }
}

// ---------------- scan kernels ----------------

__device__ __forceinline__ void lambda_of(const float* nu_log, const float* theta_log,
                                          int n, float& lre, float& lim) {
    float e = __expf(nu_log[n]);
    float th = __expf(theta_log[n]);
    float rad = __expf(-e);
    float s, c;
    __sincosf(th, &s, &c);
    lre = rad * c;
    lim = rad * s;
}

// phase 1: per (b, chunk) local scan from zero; 256 threads x 2 channels
__global__ __launch_bounds__(256) void k_scan1(const ushort* __restrict__ BuRe,
                                               const ushort* __restrict__ BuIm,
                                               const float* __restrict__ nu_log,
                                               const float* __restrict__ theta_log,
                                               float* __restrict__ cRe, float* __restrict__ cIm) {
    int n2 = threadIdx.x;              // 0..255 -> channels 2*n2, 2*n2+1
    int b = blockIdx.x >> 7;
    int c = blockIdx.x & 127;
    float lre0, lim0, lre1, lim1;
    lambda_of(nu_log, theta_log, 2 * n2, lre0, lim0);
    lambda_of(nu_log, theta_log, 2 * n2 + 1, lre1, lim1);
    float hr0 = 0.f, hi0 = 0.f, hr1 = 0.f, hi1 = 0.f;
    size_t base = ((size_t)b * T_LEN + (size_t)c * LCHUNK) * 512 + 2 * n2;
#pragma unroll 8
    for (int j = 0; j < LCHUNK; j++) {
        ushort2 ur = *(const ushort2*)(BuRe + base + (size_t)j * 512);
        ushort2 ui = *(const ushort2*)(BuIm + base + (size_t)j * 512);
        float br0 = b2f(ur.x), br1 = b2f(ur.y), bi0 = b2f(ui.x), bi1 = b2f(ui.y);
        float nr0 = lre0 * hr0 - lim0 * hi0 + br0;
        float ni0 = lre0 * hi0 + lim0 * hr0 + bi0;
        hr0 = nr0; hi0 = ni0;
        float nr1 = lre1 * hr1 - lim1 * hi1 + br1;
        float ni1 = lre1 * hi1 + lim1 * hr1 + bi1;
        hr1 = nr1; hi1 = ni1;
    }
    size_t co = ((size_t)b * NCHUNK + c) * 512 + 2 * n2;
    *(float2*)(cRe + co) = make_float2(hr0, hr1);
    *(float2*)(cIm + co) = make_float2(hi0, hi1);
}

// phase 2: combine carries across chunks; emit entering states + new_h
// newh_mode: 0 interleaved, 1 planar [re|im], 2 real only
__global__ __launch_bounds__(256) void k_scan2(const float* __restrict__ cRe,
                                               const float* __restrict__ cIm,
                                               const float* __restrict__ h0,
                                               const float* __restrict__ nu_log,
                                               const float* __restrict__ theta_log,
                                               float* __restrict__ pRe, float* __restrict__ pIm,
                                               float* __restrict__ newH, int newh_mode) {
    int idx = blockIdx.x * 256 + threadIdx.x;   // 0..4095
    int b = idx >> 9;
    int n = idx & 511;
    float lre, lim;
    lambda_of(nu_log, theta_log, n, lre, lim);
    // lambda^LCHUNK via 5 squarings (LCHUNK = 32)
    float Lr = lre, Li = lim;
#pragma unroll
    for (int s = 0; s < 5; s++) {
        float nr = Lr * Lr - Li * Li;
        float ni = 2.f * Lr * Li;
        Lr = nr; Li = ni;
    }
    float cr = h0[b * 512 + n];
    float ci = 0.f;
    for (int c = 0; c < NCHUNK; c++) {
        size_t o = ((size_t)b * NCHUNK + c) * 512 + n;
        pRe[o] = cr;
        pIm[o] = ci;
        float ar = cRe[o], ai = cIm[o];
        float nr = Lr * cr - Li * ci + ar;
        float ni = Lr * ci + Li * cr + ai;
        cr = nr; ci = ni;
    }
    size_t ci_idx = (size_t)b * 512 + n;
    if (newh_mode == 1) {
        newH[ci_idx] = cr;
        newH[(size_t)NBATCH * 512 + ci_idx] = ci;
    } else if (newh_mode == 2) {
        newH[ci_idx] = cr;
    } else {
        newH[ci_idx * 2] = cr;
        newH[ci_idx * 2 + 1] = ci;
    }
}

// phase 3: recompute local scan + lambda^{j+1}*entering, write H bf16 [re|im] rows
__global__ __launch_bounds__(256) void k_scan3(const ushort* __restrict__ BuRe,
                                               const ushort* __restrict__ BuIm,
                                               const float* __restrict__ pRe,
                                               const float* __restrict__ pIm,
                                               const float* __restrict__ nu_log,
                                               const float* __restrict__ theta_log,
                                               ushort* __restrict__ Hbf) {
    int n2 = threadIdx.x;
    int b = blockIdx.x >> 7;
    int c = blockIdx.x & 127;
    float lre0, lim0, lre1, lim1;
    lambda_of(nu_log, theta_log, 2 * n2, lre0, lim0);
    lambda_of(nu_log, theta_log, 2 * n2 + 1, lre1, lim1);
    size_t co = ((size_t)b * NCHUNK + c) * 512 + 2 * n2;
    float2 frv = *(const float2*)(pRe + co);
    float2 fiv = *(const float2*)(pIm + co);
    float fr0 = frv.x, fr1 = frv.y, fi0 = fiv.x, fi1 = fiv.y;
    float pr0 = lre0, pi0 = lim0, pr1 = lre1, pi1 = lim1;   // lambda^{j+1}
    float hr0 = 0.f, hi0 = 0.f, hr1 = 0.f, hi1 = 0.f;
    size_t row0 = (size_t)b * T_LEN + (size_t)c * LCHUNK;
#pragma unroll 4
    for (int j = 0; j < LCHUNK; j++) {
        size_t base = (row0 + j) * 512 + 2 * n2;
        ushort2 ur = *(const ushort2*)(BuRe + base);
        ushort2 ui = *(const ushort2*)(BuIm + base);
        float br0 = b2f(ur.x), br1 = b2f(ur.y), bi0 = b2f(ui.x), bi1 = b2f(ui.y);
        float nr0 = lre0 * hr0 - lim0 * hi0 + br0;
        float ni0 = lre0 * hi0 + lim0 * hr0 + bi0;
        hr0 = nr0; hi0 = ni0;
        float nr1 = lre1 * hr1 - lim1 * hi1 + br1;
        float ni1 = lre1 * hi1 + lim1 * hr1 + bi1;
        hr1 = nr1; hi1 = ni1;
        float vr0 = hr0 + pr0 * fr0 - pi0 * fi0;
        float vi0 = hi0 + pr0 * fi0 + pi0 * fr0;
        float vr1 = hr1 + pr1 * fr1 - pi1 * fi1;
        float vi1 = hi1 + pr1 * fi1 + pi1 * fr1;
        size_t hrow = (row0 + j) * 1024;
        ushort2 wre, wim;
        wre.x = f2b(vr0); wre.y = f2b(vr1);
        wim.x = f2b(vi0); wim.y = f2b(vi1);
        *(ushort2*)(Hbf + hrow + 2 * n2) = wre;
        *(ushort2*)(Hbf + hrow + 512 + 2 * n2) = wim;
        float npr0 = pr0 * lre0 - pi0 * lim0;
        float npi0 = pr0 * lim0 + pi0 * lre0;
        pr0 = npr0; pi0 = npi0;
        float npr1 = pr1 * lre1 - pi1 * lim1;
        float npi1 = pr1 * lim1 + pi1 * lre1;
        pr1 = npr1; pi1 = npi1;
    }
}

// ---------------- launch ----------------

extern "C" void kernel_launch(void* const* d_in, const int* in_sizes, int n_in,
                              void* d_out, int out_size, void* d_ws, size_t ws_size,
                              hipStream_t stream) {
    const float* x         = (const float*)d_in[0];
    const float* h0        = (const float*)d_in[1];
    const float* nu_log    = (const float*)d_in[2];
    const float* theta_log = (const float*)d_in[3];
    const float* B_re      = (const float*)d_in[4];
    const float* B_im      = (const float*)d_in[5];
    const float* C_re      = (const float*)d_in[6];
    const float* C_im      = (const float*)d_in[7];
    const float* D_param   = (const float*)d_in[8];
    const float* gamma_log = (const float*)d_in[9];

    char* ws = (char*)d_ws;
    size_t off = 0;
    ushort* Xb   = (ushort*)(ws + off); off += (size_t)MROWS * 512 * 2;        // 32 MB
    ushort* BT   = (ushort*)(ws + off); off += (size_t)1024 * 512 * 2;         // 1 MB
    ushort* CT   = (ushort*)(ws + off); off += (size_t)512 * 1024 * 2;         // 1 MB
    ushort* BuRe = (ushort*)(ws + off); off += (size_t)MROWS * 512 * 2;        // 32 MB
    ushort* BuIm = (ushort*)(ws + off); off += (size_t)MROWS * 512 * 2;        // 32 MB
    ushort* Hbf  = (ushort*)(ws + off); off += (size_t)MROWS * 1024 * 2;       // 64 MB
    float*  cRe  = (float*)(ws + off); off += (size_t)NBATCH * NCHUNK * 512 * 4;
    float*  cIm  = (float*)(ws + off); off += (size_t)NBATCH * NCHUNK * 512 * 4;
    float*  pRe  = (float*)(ws + off); off += (size_t)NBATCH * NCHUNK * 512 * 4;
    float*  pIm  = (float*)(ws + off); off += (size_t)NBATCH * NCHUNK * 512 * 4;

    float* y_out = (float*)d_out;
    float* newH  = (float*)d_out + (size_t)MROWS * 512;

    const int tail = out_size - MROWS * 512;
    int newh_mode = 0;
    if (tail == NBATCH * 512 * 2) newh_mode = 1;       // planar [re|im] (validated R2)
    else if (tail == NBATCH * 512) newh_mode = 2;

    // prep
    k_prep_x<<<dim3(MROWS * 512 / 4 / 256), dim3(256), 0, stream>>>(x, Xb);
    k_prep_B<<<dim3(1024 * 512 / 256), dim3(256), 0, stream>>>(B_re, B_im, gamma_log, BT);
    k_prep_C<<<dim3(512 * 1024 / 256), dim3(256), 0, stream>>>(C_re, C_im, CT);

    // GEMM1: Bu(bf16 planes) = Xb (32768x512) * BT^T (512x1024)
    k_gemm<512, 1><<<dim3(1024 / 128, MROWS / 128), dim3(256), 0, stream>>>(
        Xb, BT, BuRe, BuIm, nullptr, nullptr, nullptr);

    // scan
    k_scan1<<<dim3(NBATCH * NCHUNK), dim3(256), 0, stream>>>(BuRe, BuIm, nu_log, theta_log, cRe, cIm);
    k_scan2<<<dim3(NBATCH * 512 / 256), dim3(256), 0, stream>>>(cRe, cIm, h0, nu_log, theta_log, pRe, pIm, newH, newh_mode);
    k_scan3<<<dim3(NBATCH * NCHUNK), dim3(256), 0, stream>>>(BuRe, BuIm, pRe, pIm, nu_log, theta_log, Hbf);

    // GEMM2: y = Hbf (32768x1024) * CT^T (1024x512) + D*x
    k_gemm<1024, 2><<<dim3(512 / 128, MROWS / 128), dim3(256), 0, stream>>>(
        Hbf, CT, nullptr, nullptr, y_out, x, D_param);
}

// Round 4
// 292.482 us; speedup vs baseline: 1.3846x; 1.0800x over previous
//
#include <hip/hip_runtime.h>

// Problem constants
#define T_LEN 4096
#define DMODEL 512
#define DIM 512
#define NBATCH 8
#define MROWS (NBATCH * T_LEN)   // 32768
#define NCHUNK 128
#define LCHUNK 32                 // T_LEN / NCHUNK

typedef __attribute__((ext_vector_type(8))) short short8;
typedef __attribute__((ext_vector_type(4))) float float4v;

__device__ __forceinline__ ushort f2b(float f) {
    union { float fl; unsigned u; } v; v.fl = f;
    unsigned u = v.u;
    return (ushort)((u + 0x7FFFu + ((u >> 16) & 1u)) >> 16);
}
__device__ __forceinline__ float b2f(ushort u) {
    union { unsigned u; float f; } v; v.u = (unsigned)u << 16; return v.f;
}

__device__ __forceinline__ void glds16(const ushort* g, ushort* l) {
    __builtin_amdgcn_global_load_lds(
        (const __attribute__((address_space(1))) void*)g,
        (__attribute__((address_space(3))) void*)l, 16, 0, 0);
}

// ---------------- prep kernels ----------------

__global__ __launch_bounds__(256) void k_prep_x(const float* __restrict__ x,
                                                ushort* __restrict__ xb) {
    int i = (blockIdx.x * 256 + threadIdx.x) * 4;
    float4 v = *(const float4*)(x + i);
    ushort4 o;
    o.x = f2b(v.x); o.y = f2b(v.y); o.z = f2b(v.z); o.w = f2b(v.w);
    *(ushort4*)(xb + i) = o;
}

__global__ __launch_bounds__(256) void k_prep_B(const float* __restrict__ Bre,
                                                const float* __restrict__ Bim,
                                                const float* __restrict__ gamma_log,
                                                ushort* __restrict__ BT) {
    int idx = blockIdx.x * 256 + threadIdx.x;   // 0 .. 1024*512-1
    int n = idx >> 9;
    int d = idx & 511;
    float v;
    if (n < 512) v = Bre[d * 512 + n] * __expf(gamma_log[n]);
    else { int nn = n - 512; v = Bim[d * 512 + nn] * __expf(gamma_log[nn]); }
    BT[idx] = f2b(v);
}

__global__ __launch_bounds__(256) void k_prep_C(const float* __restrict__ Cre,
                                                const float* __restrict__ Cim,
                                                ushort* __restrict__ CT) {
    int idx = blockIdx.x * 256 + threadIdx.x;   // 0 .. 512*1024-1
    int d = idx >> 10;
    int k = idx & 1023;
    float v = (k < 512) ? Cre[k * 512 + d] : -Cim[(k - 512) * 512 + d];
    CT[idx] = f2b(v);
}

// ---------------- bf16 MFMA GEMM: A (MxK rm) * Bt^T (Bt NxK rm) ----------------
// BM=BN=128, BK=64, 256 thr = 4 waves 2x2, wave = 64x64 via 4x4 MFMA 16x16x32 (x2 k-steps).
// glds16 staging; LDS row = 8 chunks of 8 ushort, chunk XOR-swizzled by (row&7) to kill
// the 8/16-way ds_read_b128 bank conflict (2-way after swizzle = free).
// 1-D grid, XCD-aware remap: XCD k owns a 32-m-row band; n varies fastest within band.
template<int K, int MODE, int NBN>
__global__ __launch_bounds__(256) void k_gemm(
    const ushort* __restrict__ A, const ushort* __restrict__ Bt,
    ushort* __restrict__ oRe, ushort* __restrict__ oIm,
    float* __restrict__ y, const float* __restrict__ x, const float* __restrict__ Dp) {
    __shared__ ushort sA[128 * 64];
    __shared__ ushort sB[128 * 64];
    const int tid = threadIdx.x;
    // swizzle: assume round-robin block->XCD (L%8). XCD owns 256/8=32 m-blocks, all n.
    const int L = blockIdx.x;
    const int xcd = L & 7;
    const int slot = L >> 3;
    const int m0 = (xcd * 32 + slot / NBN) * 128;
    const int n0 = (slot % NBN) * 128;
    const int wave = tid >> 6;
    const int lane = tid & 63;
    const int wm = (wave >> 1) * 64;
    const int wn = (wave & 1) * 64;
    const int lr = lane & 15;
    const int quad = lane >> 4;

    // staging: wave w covers rows [w*32, w*32+32), 4 calls x 8 rows per matrix.
    const int srow = lane >> 3;                 // 0..7 within 8-row group
    const int schunk = (lane & 7) ^ srow;       // XOR swizzle key = row&7 = srow
    const ushort* gA0 = A + (size_t)(m0 + wave * 32 + srow) * K + schunk * 8;
    const ushort* gB0 = Bt + (size_t)(n0 + wave * 32 + srow) * K + schunk * 8;

    float4v acc[4][4];
#pragma unroll
    for (int i = 0; i < 4; i++)
#pragma unroll
        for (int j = 0; j < 4; j++) {
            float4v z = {0.f, 0.f, 0.f, 0.f};
            acc[i][j] = z;
        }

    for (int k0 = 0; k0 < K; k0 += 64) {
        __syncthreads();
#pragma unroll
        for (int c = 0; c < 4; c++) {
            glds16(gA0 + (size_t)(c * 8) * K + k0, &sA[(wave * 32 + c * 8) * 64]);
            glds16(gB0 + (size_t)(c * 8) * K + k0, &sB[(wave * 32 + c * 8) * 64]);
        }
        __syncthreads();

#pragma unroll
        for (int kk = 0; kk < 2; kk++) {
            short8 af[4], bfr[4];
#pragma unroll
            for (int i = 0; i < 4; i++) {
                int row = wm + i * 16 + lr;
                af[i] = *(const short8*)&sA[row * 64 + (((kk * 4 + quad) ^ (row & 7)) * 8)];
            }
#pragma unroll
            for (int j = 0; j < 4; j++) {
                int row = wn + j * 16 + lr;
                bfr[j] = *(const short8*)&sB[row * 64 + (((kk * 4 + quad) ^ (row & 7)) * 8)];
            }
#pragma unroll
            for (int i = 0; i < 4; i++)
#pragma unroll
                for (int j = 0; j < 4; j++)
                    acc[i][j] = __builtin_amdgcn_mfma_f32_16x16x32_bf16(af[i], bfr[j], acc[i][j], 0, 0, 0);
        }
    }

    // epilogue: D[row][col], col = lane&15, row = quad*4 + r
#pragma unroll
    for (int i = 0; i < 4; i++) {
#pragma unroll
        for (int j = 0; j < 4; j++) {
            int gmb = m0 + wm + i * 16 + quad * 4;
            int gn = n0 + wn + j * 16 + lr;
#pragma unroll
            for (int r = 0; r < 4; r++) {
                float v = acc[i][j][r];
                int row = gmb + r;
                if (MODE == 1) {
                    if (gn < 512) oRe[(size_t)row * 512 + gn] = f2b(v);
                    else oIm[(size_t)row * 512 + (gn - 512)] = f2b(v);
                } else {
                    size_t o = (size_t)row * 512 + gn;
                    y[o] = v + Dp[gn] * x[o];
                }
            }
        }
    }
}

// ---------------- scan kernels ----------------

__device__ __forceinline__ void lambda_of(const float* nu_log, const float* theta_log,
                                          int n, float& lre, float& lim) {
    float e = __expf(nu_log[n]);
    float th = __expf(theta_log[n]);
    float rad = __expf(-e);
    float s, c;
    __sincosf(th, &s, &c);
    lre = rad * c;
    lim = rad * s;
}

// phase 1: per (b, chunk) local scan from zero; 256 threads x 2 channels
__global__ __launch_bounds__(256) void k_scan1(const ushort* __restrict__ BuRe,
                                               const ushort* __restrict__ BuIm,
                                               const float* __restrict__ nu_log,
                                               const float* __restrict__ theta_log,
                                               float* __restrict__ cRe, float* __restrict__ cIm) {
    int n2 = threadIdx.x;
    int b = blockIdx.x >> 7;
    int c = blockIdx.x & 127;
    float lre0, lim0, lre1, lim1;
    lambda_of(nu_log, theta_log, 2 * n2, lre0, lim0);
    lambda_of(nu_log, theta_log, 2 * n2 + 1, lre1, lim1);
    float hr0 = 0.f, hi0 = 0.f, hr1 = 0.f, hi1 = 0.f;
    size_t base = ((size_t)b * T_LEN + (size_t)c * LCHUNK) * 512 + 2 * n2;
#pragma unroll 8
    for (int j = 0; j < LCHUNK; j++) {
        ushort2 ur = *(const ushort2*)(BuRe + base + (size_t)j * 512);
        ushort2 ui = *(const ushort2*)(BuIm + base + (size_t)j * 512);
        float br0 = b2f(ur.x), br1 = b2f(ur.y), bi0 = b2f(ui.x), bi1 = b2f(ui.y);
        float nr0 = lre0 * hr0 - lim0 * hi0 + br0;
        float ni0 = lre0 * hi0 + lim0 * hr0 + bi0;
        hr0 = nr0; hi0 = ni0;
        float nr1 = lre1 * hr1 - lim1 * hi1 + br1;
        float ni1 = lre1 * hi1 + lim1 * hr1 + bi1;
        hr1 = nr1; hi1 = ni1;
    }
    size_t co = ((size_t)b * NCHUNK + c) * 512 + 2 * n2;
    *(float2*)(cRe + co) = make_float2(hr0, hr1);
    *(float2*)(cIm + co) = make_float2(hi0, hi1);
}

// phase 2: combine carries across chunks; 64-thread blocks to spread across CUs
__global__ __launch_bounds__(64) void k_scan2(const float* __restrict__ cRe,
                                              const float* __restrict__ cIm,
                                              const float* __restrict__ h0,
                                              const float* __restrict__ nu_log,
                                              const float* __restrict__ theta_log,
                                              float* __restrict__ pRe, float* __restrict__ pIm,
                                              float* __restrict__ newH, int newh_mode) {
    int idx = blockIdx.x * 64 + threadIdx.x;   // 0..4095
    int b = idx >> 9;
    int n = idx & 511;
    float lre, lim;
    lambda_of(nu_log, theta_log, n, lre, lim);
    // lambda^LCHUNK via 5 squarings (LCHUNK = 32)
    float Lr = lre, Li = lim;
#pragma unroll
    for (int s = 0; s < 5; s++) {
        float nr = Lr * Lr - Li * Li;
        float ni = 2.f * Lr * Li;
        Lr = nr; Li = ni;
    }
    float cr = h0[b * 512 + n];
    float ci = 0.f;
#pragma unroll 4
    for (int c = 0; c < NCHUNK; c++) {
        size_t o = ((size_t)b * NCHUNK + c) * 512 + n;
        pRe[o] = cr;
        pIm[o] = ci;
        float ar = cRe[o], ai = cIm[o];
        float nr = Lr * cr - Li * ci + ar;
        float ni = Lr * ci + Li * cr + ai;
        cr = nr; ci = ni;
    }
    size_t ci_idx = (size_t)b * 512 + n;
    if (newh_mode == 1) {
        newH[ci_idx] = cr;
        newH[(size_t)NBATCH * 512 + ci_idx] = ci;
    } else if (newh_mode == 2) {
        newH[ci_idx] = cr;
    } else {
        newH[ci_idx * 2] = cr;
        newH[ci_idx * 2 + 1] = ci;
    }
}

// phase 3: recompute local scan + lambda^{j+1}*entering, write H bf16 [re|im] rows
__global__ __launch_bounds__(256) void k_scan3(const ushort* __restrict__ BuRe,
                                               const ushort* __restrict__ BuIm,
                                               const float* __restrict__ pRe,
                                               const float* __restrict__ pIm,
                                               const float* __restrict__ nu_log,
                                               const float* __restrict__ theta_log,
                                               ushort* __restrict__ Hbf) {
    int n2 = threadIdx.x;
    int b = blockIdx.x >> 7;
    int c = blockIdx.x & 127;
    float lre0, lim0, lre1, lim1;
    lambda_of(nu_log, theta_log, 2 * n2, lre0, lim0);
    lambda_of(nu_log, theta_log, 2 * n2 + 1, lre1, lim1);
    size_t co = ((size_t)b * NCHUNK + c) * 512 + 2 * n2;
    float2 frv = *(const float2*)(pRe + co);
    float2 fiv = *(const float2*)(pIm + co);
    float fr0 = frv.x, fr1 = frv.y, fi0 = fiv.x, fi1 = fiv.y;
    float pr0 = lre0, pi0 = lim0, pr1 = lre1, pi1 = lim1;
    float hr0 = 0.f, hi0 = 0.f, hr1 = 0.f, hi1 = 0.f;
    size_t row0 = (size_t)b * T_LEN + (size_t)c * LCHUNK;
#pragma unroll 4
    for (int j = 0; j < LCHUNK; j++) {
        size_t base = (row0 + j) * 512 + 2 * n2;
        ushort2 ur = *(const ushort2*)(BuRe + base);
        ushort2 ui = *(const ushort2*)(BuIm + base);
        float br0 = b2f(ur.x), br1 = b2f(ur.y), bi0 = b2f(ui.x), bi1 = b2f(ui.y);
        float nr0 = lre0 * hr0 - lim0 * hi0 + br0;
        float ni0 = lre0 * hi0 + lim0 * hr0 + bi0;
        hr0 = nr0; hi0 = ni0;
        float nr1 = lre1 * hr1 - lim1 * hi1 + br1;
        float ni1 = lre1 * hi1 + lim1 * hr1 + bi1;
        hr1 = nr1; hi1 = ni1;
        float vr0 = hr0 + pr0 * fr0 - pi0 * fi0;
        float vi0 = hi0 + pr0 * fi0 + pi0 * fr0;
        float vr1 = hr1 + pr1 * fr1 - pi1 * fi1;
        float vi1 = hi1 + pr1 * fi1 + pi1 * fr1;
        size_t hrow = (row0 + j) * 1024;
        ushort2 wre, wim;
        wre.x = f2b(vr0); wre.y = f2b(vr1);
        wim.x = f2b(vi0); wim.y = f2b(vi1);
        *(ushort2*)(Hbf + hrow + 2 * n2) = wre;
        *(ushort2*)(Hbf + hrow + 512 + 2 * n2) = wim;
        float npr0 = pr0 * lre0 - pi0 * lim0;
        float npi0 = pr0 * lim0 + pi0 * lre0;
        pr0 = npr0; pi0 = npi0;
        float npr1 = pr1 * lre1 - pi1 * lim1;
        float npi1 = pr1 * lim1 + pi1 * lre1;
        pr1 = npr1; pi1 = npi1;
    }
}

// ---------------- launch ----------------

extern "C" void kernel_launch(void* const* d_in, const int* in_sizes, int n_in,
                              void* d_out, int out_size, void* d_ws, size_t ws_size,
                              hipStream_t stream) {
    const float* x         = (const float*)d_in[0];
    const float* h0        = (const float*)d_in[1];
    const float* nu_log    = (const float*)d_in[2];
    const float* theta_log = (const float*)d_in[3];
    const float* B_re      = (const float*)d_in[4];
    const float* B_im      = (const float*)d_in[5];
    const float* C_re      = (const float*)d_in[6];
    const float* C_im      = (const float*)d_in[7];
    const float* D_param   = (const float*)d_in[8];
    const float* gamma_log = (const float*)d_in[9];

    char* ws = (char*)d_ws;
    size_t off = 0;
    ushort* Xb   = (ushort*)(ws + off); off += (size_t)MROWS * 512 * 2;
    ushort* BT   = (ushort*)(ws + off); off += (size_t)1024 * 512 * 2;
    ushort* CT   = (ushort*)(ws + off); off += (size_t)512 * 1024 * 2;
    ushort* BuRe = (ushort*)(ws + off); off += (size_t)MROWS * 512 * 2;
    ushort* BuIm = (ushort*)(ws + off); off += (size_t)MROWS * 512 * 2;
    ushort* Hbf  = (ushort*)(ws + off); off += (size_t)MROWS * 1024 * 2;
    float*  cRe  = (float*)(ws + off); off += (size_t)NBATCH * NCHUNK * 512 * 4;
    float*  cIm  = (float*)(ws + off); off += (size_t)NBATCH * NCHUNK * 512 * 4;
    float*  pRe  = (float*)(ws + off); off += (size_t)NBATCH * NCHUNK * 512 * 4;
    float*  pIm  = (float*)(ws + off); off += (size_t)NBATCH * NCHUNK * 512 * 4;

    float* y_out = (float*)d_out;
    float* newH  = (float*)d_out + (size_t)MROWS * 512;

    const int tail = out_size - MROWS * 512;
    int newh_mode = 0;
    if (tail == NBATCH * 512 * 2) newh_mode = 1;       // planar [re|im] (validated R2)
    else if (tail == NBATCH * 512) newh_mode = 2;

    // prep
    k_prep_x<<<dim3(MROWS * 512 / 4 / 256), dim3(256), 0, stream>>>(x, Xb);
    k_prep_B<<<dim3(1024 * 512 / 256), dim3(256), 0, stream>>>(B_re, B_im, gamma_log, BT);
    k_prep_C<<<dim3(512 * 1024 / 256), dim3(256), 0, stream>>>(C_re, C_im, CT);

    // GEMM1: Bu(bf16 planes) = Xb (32768x512) * BT^T (512x1024); 2048 blocks
    k_gemm<512, 1, 8><<<dim3(2048), dim3(256), 0, stream>>>(
        Xb, BT, BuRe, BuIm, nullptr, nullptr, nullptr);

    // scan
    k_scan1<<<dim3(NBATCH * NCHUNK), dim3(256), 0, stream>>>(BuRe, BuIm, nu_log, theta_log, cRe, cIm);
    k_scan2<<<dim3(NBATCH * 512 / 64), dim3(64), 0, stream>>>(cRe, cIm, h0, nu_log, theta_log, pRe, pIm, newH, newh_mode);
    k_scan3<<<dim3(NBATCH * NCHUNK), dim3(256), 0, stream>>>(BuRe, BuIm, pRe, pIm, nu_log, theta_log, Hbf);

    // GEMM2: y = Hbf (32768x1024) * CT^T (1024x512) + D*x; 1024 blocks
    k_gemm<1024, 2, 4><<<dim3(1024), dim3(256), 0, stream>>>(
        Hbf, CT, nullptr, nullptr, y_out, x, D_param);
}